// Round 3
// 304.047 us; speedup vs baseline: 1.0094x; 1.0094x over previous
//
#include <hip/hip_runtime.h>
#include <math.h>

// Problem constants (fixed by setup_inputs)
constexpr int B  = 8;
constexpr int CF = 256;
constexpr int HF = 128;
constexpr int WF = 128;
constexpr int HP = 512;
constexpr int WP = 512;
constexpr long long NTOT = (long long)B * CF * HF * WF;   // 33,554,432

typedef float f4 __attribute__((ext_vector_type(4)));

// ws layout (bytes):
//   [0, 8)              : float meanf, float rstd
//   [256, 256+512K)     : D_h (8*128*128 f32) -- pooled mask, dilated in place
//   [IMG_OFF, +1.5M)    : img_ds (8*3*128*128 f32)
//   [PART_OFF, +32K)    : per-block double2 partials
constexpr size_t STATS_OFF = 0;
constexpr size_t DH_OFF    = 256;
constexpr size_t IMG_OFF   = DH_OFF + (size_t)B * HF * WF * sizeof(float);
constexpr size_t PART_OFF  = IMG_OFF + (size_t)B * 3 * HF * WF * sizeof(float);

constexpr int RBLOCKS  = 2048;
constexpr int RTHREADS = 256;
constexpr int PBLOCKS  = 512;   // pool blocks fused in front of the reduce grid
// each reduce thread loads 16 float4 chunks spaced CH_S apart
constexpr long long CH_S = (long long)RBLOCKS * RTHREADS * 4;   // 2,097,152 floats
// 16 * CH_S = NTOT exactly.

// Fused pass 1:
//   blocks [0, PBLOCKS)            : 4x4 avg-pool img (3ch) + 4x4 max-pool mask ch0
//   blocks [PBLOCKS, PBLOCKS+2048) : per-block partial sum/sumsq over F
// Pool work (6 us of traffic) hides under the 22 us reduce stream; saves one
// launch + serialization vs the previous 2-kernel version.
__global__ void __launch_bounds__(RTHREADS) k_reduce_pool(
        const float* __restrict__ F,
        const float* __restrict__ img, const float* __restrict__ mask,
        float* __restrict__ img_ds, float* __restrict__ mds,
        double2* __restrict__ part) {
    __shared__ double ls[4], lq[4];
    const int bid = blockIdx.x;
    if (bid < PBLOCKS) {
        // ---- pool path (block-uniform branch) ----
        int t = bid * RTHREADS + threadIdx.x;        // [0, 131072) exactly
        int w = t & (WF - 1);
        int h = (t >> 7) & (HF - 1);
        int b = t >> 14;
        for (int c = 0; c < 3; ++c) {
            const float* p = img + (((b * 3 + c) * HP + h * 4) * WP + w * 4);
            float s = 0.0f;
            for (int r = 0; r < 4; ++r) {
                f4 v = *(const f4*)(p + r * WP);
                s += v.x + v.y + v.z + v.w;
            }
            img_ds[((b * 3 + c) << 14) | (h << 7) | w] = s * 0.0625f;
        }
        const float* pm = mask + (((b * 3) * HP + h * 4) * WP + w * 4);
        float m = 0.0f;
        for (int r = 0; r < 4; ++r) {
            f4 v = *(const f4*)(pm + r * WP);
            m = fmaxf(m, fmaxf(fmaxf(v.x, v.y), fmaxf(v.z, v.w)));
        }
        mds[t] = m;
        return;
    }
    // ---- reduce path ----
    const int rb = bid - PBLOCKS;
    const long long tid = (long long)rb * RTHREADS + threadIdx.x;
    const float* p = F + tid * 4;
    f4 v[16];
#pragma unroll
    for (int k = 0; k < 16; ++k)
        v[k] = *(const f4*)(p + k * CH_S);
    double s0 = 0, s1 = 0, s2 = 0, s3 = 0;
    double q0 = 0, q1 = 0, q2 = 0, q3 = 0;
#pragma unroll
    for (int k = 0; k < 16; k += 4) {
        {
            f4 w = v[k + 0];
            s0 += (double)((w.x + w.y) + (w.z + w.w));
            q0 += (double)((w.x * w.x + w.y * w.y) + (w.z * w.z + w.w * w.w));
        }
        {
            f4 w = v[k + 1];
            s1 += (double)((w.x + w.y) + (w.z + w.w));
            q1 += (double)((w.x * w.x + w.y * w.y) + (w.z * w.z + w.w * w.w));
        }
        {
            f4 w = v[k + 2];
            s2 += (double)((w.x + w.y) + (w.z + w.w));
            q2 += (double)((w.x * w.x + w.y * w.y) + (w.z * w.z + w.w * w.w));
        }
        {
            f4 w = v[k + 3];
            s3 += (double)((w.x + w.y) + (w.z + w.w));
            q3 += (double)((w.x * w.x + w.y * w.y) + (w.z * w.z + w.w * w.w));
        }
    }
    double s = (s0 + s1) + (s2 + s3);
    double q = (q0 + q1) + (q2 + q3);
    for (int off = 32; off > 0; off >>= 1) {
        s += __shfl_down(s, off);
        q += __shfl_down(q, off);
    }
    int lane = threadIdx.x & 63, wv = threadIdx.x >> 6;
    if (lane == 0) { ls[wv] = s; lq[wv] = q; }
    __syncthreads();
    if (threadIdx.x == 0) {
        double S_ = 0.0, Q_ = 0.0;
        for (int w = 0; w < 4; ++w) { S_ += ls[w]; Q_ += lq[w]; }
        part[rb] = make_double2(S_, Q_);
    }
}

// blocks 0..7: 5-iter masked dilation (capped Chebyshev DT) in LDS, in place.
// block 8: reduce the 2048 double2 partials -> stats {meanf, rstd}.
__global__ void __launch_bounds__(1024) k_dilate_stats(float* __restrict__ Dh,
                                                       const double2* __restrict__ part,
                                                       float* __restrict__ stats) {
    if (blockIdx.x == 8) {
        double s = 0.0, q = 0.0;
        for (int i = threadIdx.x; i < RBLOCKS; i += 1024) {
            double2 p = part[i];
            s += p.x; q += p.y;
        }
        for (int off = 32; off > 0; off >>= 1) {
            s += __shfl_down(s, off);
            q += __shfl_down(q, off);
        }
        __shared__ double ls[16], lq[16];
        int lane = threadIdx.x & 63, wv = threadIdx.x >> 6;
        if (lane == 0) { ls[wv] = s; lq[wv] = q; }
        __syncthreads();
        if (threadIdx.x == 0) {
            double S_ = 0.0, Q_ = 0.0;
            for (int w = 0; w < 16; ++w) { S_ += ls[w]; Q_ += lq[w]; }
            double mean = S_ / (double)NTOT;
            double var  = (Q_ - (double)NTOT * mean * mean) / (double)(NTOT - 1);
            stats[0] = (float)mean;
            stats[1] = (float)(1.0 / sqrt(var * var + 1e-5));
        }
        return;
    }
    __shared__ float M[HF * WF];   // 64 KB
    const int b = blockIdx.x;
    float* img = Dh + b * HF * WF;
    for (int i = threadIdx.x; i < HF * WF; i += 1024) M[i] = img[i];
    __syncthreads();
    float invk = 1.0f;
    for (int it = 1; it <= 5; ++it) {
        invk *= 0.5f;
        unsigned nf = 0;
        for (int j = 0; j < 16; ++j) {
            int p = threadIdx.x + j * 1024;
            if (M[p] != 0.0f) continue;
            int h = p >> 7, w = p & 127;
            bool any = false;
            for (int dh = -1; dh <= 1; ++dh) {
                int hh = h + dh;
                if (hh < 0 || hh >= HF) continue;
                for (int dw = -1; dw <= 1; ++dw) {
                    int ww = w + dw;
                    if (ww < 0 || ww >= WF) continue;
                    any = any || (M[(hh << 7) | ww] > 0.0f);
                }
            }
            if (any) nf |= (1u << j);
        }
        __syncthreads();
        for (int j = 0; j < 16; ++j)
            if (nf & (1u << j)) M[threadIdx.x + j * 1024] = invk;
        __syncthreads();
    }
    for (int i = threadIdx.x; i < HF * WF; i += 1024) img[i] = M[i];
}

// Fused epilogue, channel-grouped: each thread does 4 w-elems x 8 channels,
// reusing the per-pixel D/R/G/B gather across channels.
//  - (ib, icg) derived from blockIdx => provably block-uniform => the 64
//    coefficient loads per thread become s_loads.
//  - F read is a PLAIN load (L3-residency probe: F was fully touched by the
//    reduce pass with allocating loads and fits the 256 MiB LLC; if the old
//    NT load was skipping the LLC this is worth ~18 us).
//  - out store stays NT (no-allocate) so the write stream can't evict F.
constexpr int CGRP = 8;
__global__ void __launch_bounds__(256) k_final(const float* __restrict__ F,
                        const float* __restrict__ img_ds,
                        const float* __restrict__ Dh,
                        const float* __restrict__ gw, const float* __restrict__ gb,
                        const float* __restrict__ bw, const float* __restrict__ bb,
                        const float* __restrict__ stats,
                        float* __restrict__ out) {
    // grid = 4096 blocks x 256 threads.
    // blockIdx bits: [0:4) ih_hi, [4:9) icg, [9:12) ib   (all block-uniform)
    // threadIdx bits: [0:5) iw, [5:8) ih_lo
    const int ihh = blockIdx.x & 15;
    const int icg = (blockIdx.x >> 4) & 31;
    const int ib  = blockIdx.x >> 9;
    const int iw  = threadIdx.x & 31;
    const int ih  = (ihh << 3) | (threadIdx.x >> 5);
    const int w   = iw * 4;
    const int c0  = icg * CGRP;

    const float meanf = stats[0];
    const float rstd  = stats[1];

    const int pixoff = (ih << 7) | w;
    const int pix = (ib << 14) | pixoff;
    f4 D = *(const f4*)(Dh + pix);
    const float* ip = img_ds + ((size_t)ib * 3 << 14);
    f4 R  = *(const f4*)(ip + ((0 << 14) | pixoff));
    f4 G  = *(const f4*)(ip + ((1 << 14) | pixoff));
    f4 Bl = *(const f4*)(ip + ((2 << 14) | pixoff));

    const size_t fbase = (((size_t)(ib * CF + c0)) << 14) + pixoff;

    f4 Fv[CGRP];
#pragma unroll
    for (int j = 0; j < CGRP; ++j)
        Fv[j] = *(const f4*)(F + fbase + ((size_t)j << 14));

#pragma unroll
    for (int j = 0; j < CGRP; ++j) {
        const int c = c0 + j;
        float g0 = gw[c * 3], g1 = gw[c * 3 + 1], g2 = gw[c * 3 + 2], gbi = gb[c];
        float b0 = bw[c * 3], b1 = bw[c * 3 + 1], b2 = bw[c * 3 + 2], bbi = bb[c];
        f4 o;
        {
            float gam = (R.x * g0 + G.x * g1 + Bl.x * g2 + gbi) * D.x;
            float bet = (R.x * b0 + G.x * b1 + Bl.x * b2 + bbi) * D.x;
            o.x = (Fv[j].x - meanf) * rstd * gam + bet;
        }
        {
            float gam = (R.y * g0 + G.y * g1 + Bl.y * g2 + gbi) * D.y;
            float bet = (R.y * b0 + G.y * b1 + Bl.y * b2 + bbi) * D.y;
            o.y = (Fv[j].y - meanf) * rstd * gam + bet;
        }
        {
            float gam = (R.z * g0 + G.z * g1 + Bl.z * g2 + gbi) * D.z;
            float bet = (R.z * b0 + G.z * b1 + Bl.z * b2 + bbi) * D.z;
            o.z = (Fv[j].z - meanf) * rstd * gam + bet;
        }
        {
            float gam = (R.w * g0 + G.w * g1 + Bl.w * g2 + gbi) * D.w;
            float bet = (R.w * b0 + G.w * b1 + Bl.w * b2 + bbi) * D.w;
            o.w = (Fv[j].w - meanf) * rstd * gam + bet;
        }
        __builtin_nontemporal_store(o, (f4*)(out + fbase + ((size_t)j << 14)));
    }
}

extern "C" void kernel_launch(void* const* d_in, const int* in_sizes, int n_in,
                              void* d_out, int out_size, void* d_ws, size_t ws_size,
                              hipStream_t stream) {
    const float* F_in  = (const float*)d_in[0];
    const float* img_p = (const float*)d_in[1];
    const float* mask  = (const float*)d_in[2];
    const float* gw    = (const float*)d_in[3];
    const float* gb    = (const float*)d_in[4];
    const float* bw    = (const float*)d_in[5];
    const float* bb    = (const float*)d_in[6];
    float* out = (float*)d_out;

    float*   stats  = (float*)((char*)d_ws + STATS_OFF);
    float*   Dh     = (float*)((char*)d_ws + DH_OFF);
    float*   img_ds = (float*)((char*)d_ws + IMG_OFF);
    double2* part   = (double2*)((char*)d_ws + PART_OFF);

    k_reduce_pool<<<PBLOCKS + RBLOCKS, RTHREADS, 0, stream>>>(
        F_in, img_p, mask, img_ds, Dh, part);
    k_dilate_stats<<<B + 1, 1024, 0, stream>>>(Dh, part, stats);
    k_final<<<(int)(NTOT / (4 * CGRP) / 256), 256, 0, stream>>>(
        F_in, img_ds, Dh, gw, gb, bw, bb, stats, out);
}

// Round 4
// 300.212 us; speedup vs baseline: 1.0223x; 1.0128x over previous
//
#include <hip/hip_runtime.h>
#include <math.h>

// Problem constants (fixed by setup_inputs)
constexpr int B  = 8;
constexpr int CF = 256;
constexpr int HF = 128;
constexpr int WF = 128;
constexpr int HP = 512;
constexpr int WP = 512;
constexpr long long NTOT = (long long)B * CF * HF * WF;   // 33,554,432

typedef float f4 __attribute__((ext_vector_type(4)));

// ws layout (bytes):
//   [0, 8)              : float meanf, float rstd
//   [256, 256+512K)     : D_h (8*128*128 f32) -- pooled mask, dilated in place
//   [IMG_OFF, +1.5M)    : img_ds (8*3*128*128 f32)
//   [PART_OFF, +32K)    : per-block double2 partials
constexpr size_t STATS_OFF = 0;
constexpr size_t DH_OFF    = 256;
constexpr size_t IMG_OFF   = DH_OFF + (size_t)B * HF * WF * sizeof(float);
constexpr size_t PART_OFF  = IMG_OFF + (size_t)B * 3 * HF * WF * sizeof(float);

constexpr int RBLOCKS  = 2048;
constexpr int RTHREADS = 256;
constexpr int PBLOCKS  = 512;   // pool blocks fused in front of the reduce grid
// Each reduce block owns a CONTIGUOUS 16384-float (64 KB) region and streams
// through it in 16 sequential 4 KB steps. (Round-3 counters: the old
// 8MB-strided chunk pattern ran at 1.1 TB/s HBM / 2.2 TB/s effective --
// scattered 4KB chunks kill DRAM row locality. The 6.8 TB/s fill kernels
// stream contiguously; mimic that.)
constexpr int RCHUNK = 16384;                    // floats per block
// 2048 * 16384 = 33,554,432 = NTOT exactly.

// Fused pass 1:
//   blocks [0, PBLOCKS)            : 4x4 avg-pool img (3ch) + 4x4 max-pool mask ch0
//   blocks [PBLOCKS, PBLOCKS+2048) : per-block partial sum/sumsq over F
__global__ void __launch_bounds__(RTHREADS) k_reduce_pool(
        const float* __restrict__ F,
        const float* __restrict__ img, const float* __restrict__ mask,
        float* __restrict__ img_ds, float* __restrict__ mds,
        double2* __restrict__ part) {
    __shared__ double ls[4], lq[4];
    const int bid = blockIdx.x;
    if (bid < PBLOCKS) {
        // ---- pool path (block-uniform branch) ----
        int t = bid * RTHREADS + threadIdx.x;        // [0, 131072) exactly
        int w = t & (WF - 1);
        int h = (t >> 7) & (HF - 1);
        int b = t >> 14;
        for (int c = 0; c < 3; ++c) {
            const float* p = img + (((b * 3 + c) * HP + h * 4) * WP + w * 4);
            float s = 0.0f;
            for (int r = 0; r < 4; ++r) {
                f4 v = *(const f4*)(p + r * WP);
                s += v.x + v.y + v.z + v.w;
            }
            img_ds[((b * 3 + c) << 14) | (h << 7) | w] = s * 0.0625f;
        }
        const float* pm = mask + (((b * 3) * HP + h * 4) * WP + w * 4);
        float m = 0.0f;
        for (int r = 0; r < 4; ++r) {
            f4 v = *(const f4*)(pm + r * WP);
            m = fmaxf(m, fmaxf(fmaxf(v.x, v.y), fmaxf(v.z, v.w)));
        }
        mds[t] = m;
        return;
    }
    // ---- reduce path: contiguous 64 KB stream per block ----
    const int rb = bid - PBLOCKS;
    const float* p = F + (size_t)rb * RCHUNK + threadIdx.x * 4;
    f4 v[16];
#pragma unroll
    for (int k = 0; k < 16; ++k)
        v[k] = *(const f4*)(p + k * (RTHREADS * 4));   // sequential 4 KB steps
    double s0 = 0, s1 = 0, s2 = 0, s3 = 0;
    double q0 = 0, q1 = 0, q2 = 0, q3 = 0;
#pragma unroll
    for (int k = 0; k < 16; k += 4) {
        {
            f4 w = v[k + 0];
            s0 += (double)((w.x + w.y) + (w.z + w.w));
            q0 += (double)((w.x * w.x + w.y * w.y) + (w.z * w.z + w.w * w.w));
        }
        {
            f4 w = v[k + 1];
            s1 += (double)((w.x + w.y) + (w.z + w.w));
            q1 += (double)((w.x * w.x + w.y * w.y) + (w.z * w.z + w.w * w.w));
        }
        {
            f4 w = v[k + 2];
            s2 += (double)((w.x + w.y) + (w.z + w.w));
            q2 += (double)((w.x * w.x + w.y * w.y) + (w.z * w.z + w.w * w.w));
        }
        {
            f4 w = v[k + 3];
            s3 += (double)((w.x + w.y) + (w.z + w.w));
            q3 += (double)((w.x * w.x + w.y * w.y) + (w.z * w.z + w.w * w.w));
        }
    }
    double s = (s0 + s1) + (s2 + s3);
    double q = (q0 + q1) + (q2 + q3);
    for (int off = 32; off > 0; off >>= 1) {
        s += __shfl_down(s, off);
        q += __shfl_down(q, off);
    }
    int lane = threadIdx.x & 63, wv = threadIdx.x >> 6;
    if (lane == 0) { ls[wv] = s; lq[wv] = q; }
    __syncthreads();
    if (threadIdx.x == 0) {
        double S_ = 0.0, Q_ = 0.0;
        for (int w = 0; w < 4; ++w) { S_ += ls[w]; Q_ += lq[w]; }
        part[rb] = make_double2(S_, Q_);
    }
}

// blocks 0..7: 5-iter masked dilation (capped Chebyshev DT) in LDS, in place.
// block 8: reduce the 2048 double2 partials -> stats {meanf, rstd}.
__global__ void __launch_bounds__(1024) k_dilate_stats(float* __restrict__ Dh,
                                                       const double2* __restrict__ part,
                                                       float* __restrict__ stats) {
    if (blockIdx.x == 8) {
        double s = 0.0, q = 0.0;
        for (int i = threadIdx.x; i < RBLOCKS; i += 1024) {
            double2 p = part[i];
            s += p.x; q += p.y;
        }
        for (int off = 32; off > 0; off >>= 1) {
            s += __shfl_down(s, off);
            q += __shfl_down(q, off);
        }
        __shared__ double ls[16], lq[16];
        int lane = threadIdx.x & 63, wv = threadIdx.x >> 6;
        if (lane == 0) { ls[wv] = s; lq[wv] = q; }
        __syncthreads();
        if (threadIdx.x == 0) {
            double S_ = 0.0, Q_ = 0.0;
            for (int w = 0; w < 16; ++w) { S_ += ls[w]; Q_ += lq[w]; }
            double mean = S_ / (double)NTOT;
            double var  = (Q_ - (double)NTOT * mean * mean) / (double)(NTOT - 1);
            stats[0] = (float)mean;
            stats[1] = (float)(1.0 / sqrt(var * var + 1e-5));
        }
        return;
    }
    __shared__ float M[HF * WF];   // 64 KB
    const int b = blockIdx.x;
    float* img = Dh + b * HF * WF;
    for (int i = threadIdx.x; i < HF * WF; i += 1024) M[i] = img[i];
    __syncthreads();
    float invk = 1.0f;
    for (int it = 1; it <= 5; ++it) {
        invk *= 0.5f;
        unsigned nf = 0;
        for (int j = 0; j < 16; ++j) {
            int p = threadIdx.x + j * 1024;
            if (M[p] != 0.0f) continue;
            int h = p >> 7, w = p & 127;
            bool any = false;
            for (int dh = -1; dh <= 1; ++dh) {
                int hh = h + dh;
                if (hh < 0 || hh >= HF) continue;
                for (int dw = -1; dw <= 1; ++dw) {
                    int ww = w + dw;
                    if (ww < 0 || ww >= WF) continue;
                    any = any || (M[(hh << 7) | ww] > 0.0f);
                }
            }
            if (any) nf |= (1u << j);
        }
        __syncthreads();
        for (int j = 0; j < 16; ++j)
            if (nf & (1u << j)) M[threadIdx.x + j * 1024] = invk;
        __syncthreads();
    }
    for (int i = threadIdx.x; i < HF * WF; i += 1024) img[i] = M[i];
}

// Fused epilogue, channel-grouped. Each block now covers 32 consecutive rows
// (4 sub-steps of 8 rows), so its 8 F-read streams and 8 store streams each
// advance contiguously 4 KB per sub-step (16 KB sequential per channel chunk)
// instead of one scattered 4 KB shot -- same DRAM row-locality theory as the
// reduce fix. Coefficient scalar loads amortized 4x.
constexpr int CGRP = 8;
__global__ void __launch_bounds__(256) k_final(const float* __restrict__ F,
                        const float* __restrict__ img_ds,
                        const float* __restrict__ Dh,
                        const float* __restrict__ gw, const float* __restrict__ gb,
                        const float* __restrict__ bw, const float* __restrict__ bb,
                        const float* __restrict__ stats,
                        float* __restrict__ out) {
    // grid = 1024 blocks x 256 threads.
    // blockIdx bits: [0:2) ihh4, [2:7) icg, [7:10) ib   (all block-uniform)
    // threadIdx bits: [0:5) iw, [5:8) ih_lo
    const int ihh4 = blockIdx.x & 3;
    const int icg  = (blockIdx.x >> 2) & 31;
    const int ib   = blockIdx.x >> 7;
    const int iw   = threadIdx.x & 31;
    const int w4   = iw * 4;
    const int c0   = icg * CGRP;

    const float meanf = stats[0];
    const float rstd  = stats[1];

    // hoist coefficients out of the row loop (block-uniform -> s_loads)
    float g0[CGRP], g1[CGRP], g2[CGRP], gbi[CGRP];
    float b0[CGRP], b1[CGRP], b2[CGRP], bbi[CGRP];
#pragma unroll
    for (int j = 0; j < CGRP; ++j) {
        const int c = c0 + j;
        g0[j] = gw[c * 3]; g1[j] = gw[c * 3 + 1]; g2[j] = gw[c * 3 + 2];
        gbi[j] = gb[c];
        b0[j] = bw[c * 3]; b1[j] = bw[c * 3 + 1]; b2[j] = bw[c * 3 + 2];
        bbi[j] = bb[c];
    }

    const float* ip = img_ds + ((size_t)ib * 3 << 14);

#pragma unroll
    for (int sub = 0; sub < 4; ++sub) {
        const int ih = ihh4 * 32 + sub * 8 + (threadIdx.x >> 5);
        const int pixoff = (ih << 7) | w4;
        const int pix = (ib << 14) | pixoff;
        f4 D  = *(const f4*)(Dh + pix);
        f4 R  = *(const f4*)(ip + ((0 << 14) | pixoff));
        f4 G  = *(const f4*)(ip + ((1 << 14) | pixoff));
        f4 Bl = *(const f4*)(ip + ((2 << 14) | pixoff));

        const size_t fbase = (((size_t)(ib * CF + c0)) << 14) + pixoff;

        f4 Fv[CGRP];
#pragma unroll
        for (int j = 0; j < CGRP; ++j)
            Fv[j] = *(const f4*)(F + fbase + ((size_t)j << 14));

#pragma unroll
        for (int j = 0; j < CGRP; ++j) {
            f4 o;
            {
                float gam = (R.x * g0[j] + G.x * g1[j] + Bl.x * g2[j] + gbi[j]) * D.x;
                float bet = (R.x * b0[j] + G.x * b1[j] + Bl.x * b2[j] + bbi[j]) * D.x;
                o.x = (Fv[j].x - meanf) * rstd * gam + bet;
            }
            {
                float gam = (R.y * g0[j] + G.y * g1[j] + Bl.y * g2[j] + gbi[j]) * D.y;
                float bet = (R.y * b0[j] + G.y * b1[j] + Bl.y * b2[j] + bbi[j]) * D.y;
                o.y = (Fv[j].y - meanf) * rstd * gam + bet;
            }
            {
                float gam = (R.z * g0[j] + G.z * g1[j] + Bl.z * g2[j] + gbi[j]) * D.z;
                float bet = (R.z * b0[j] + G.z * b1[j] + Bl.z * b2[j] + bbi[j]) * D.z;
                o.z = (Fv[j].z - meanf) * rstd * gam + bet;
            }
            {
                float gam = (R.w * g0[j] + G.w * g1[j] + Bl.w * g2[j] + gbi[j]) * D.w;
                float bet = (R.w * b0[j] + G.w * b1[j] + Bl.w * b2[j] + bbi[j]) * D.w;
                o.w = (Fv[j].w - meanf) * rstd * gam + bet;
            }
            __builtin_nontemporal_store(o, (f4*)(out + fbase + ((size_t)j << 14)));
        }
    }
}

extern "C" void kernel_launch(void* const* d_in, const int* in_sizes, int n_in,
                              void* d_out, int out_size, void* d_ws, size_t ws_size,
                              hipStream_t stream) {
    const float* F_in  = (const float*)d_in[0];
    const float* img_p = (const float*)d_in[1];
    const float* mask  = (const float*)d_in[2];
    const float* gw    = (const float*)d_in[3];
    const float* gb    = (const float*)d_in[4];
    const float* bw    = (const float*)d_in[5];
    const float* bb    = (const float*)d_in[6];
    float* out = (float*)d_out;

    float*   stats  = (float*)((char*)d_ws + STATS_OFF);
    float*   Dh     = (float*)((char*)d_ws + DH_OFF);
    float*   img_ds = (float*)((char*)d_ws + IMG_OFF);
    double2* part   = (double2*)((char*)d_ws + PART_OFF);

    k_reduce_pool<<<PBLOCKS + RBLOCKS, RTHREADS, 0, stream>>>(
        F_in, img_p, mask, img_ds, Dh, part);
    k_dilate_stats<<<B + 1, 1024, 0, stream>>>(Dh, part, stats);
    k_final<<<8 * 32 * 4, 256, 0, stream>>>(
        F_in, img_ds, Dh, gw, gb, bw, bb, stats, out);
}